// Round 12
// baseline (13.703 us; speedup 1.0000x reference)
//
#include <hip/hip_runtime.h>
#include <math.h>

#define BB 128
#define CC 1024
#define SPLIT 16                 // windows (blocks) per batch
#define NBLK (BB * SPLIT)        // 2048
#define INV_N (1.0f / (float)(BB * CC))

// Spread 16 bits to stride-4 positions of a 64-bit word (morton-style).
__device__ __forceinline__ unsigned long long spread4(unsigned long long u) {
  u &= 0xFFFFull;
  u = (u | (u << 24)) & 0x000000FF000000FFull;
  u = (u | (u << 12)) & 0x000F000F000F000Full;
  u = (u | (u << 6))  & 0x0303030303030303ull;
  u = (u | (u << 3))  & 0x1111111111111111ull;
  return u;
}

// Block (b,c): batch b, window of 64 columns/rows [64c, 64c+64).
// No compaction, no LDS: w[j] = x_j^2 * y_j lives in registers; positives
// found via 4 ballots + scalar bit-spread; mask rows read fully coalesced
// (float4), 4 rows fused per round; pairwise half-mux butterfly reductions.
__global__ __launch_bounds__(64) void asl_main_kernel(
    const float* __restrict__ x, const float* __restrict__ y,
    const float* __restrict__ mask, float* __restrict__ partial) {
  const int blk  = blockIdx.x;
  const int b    = blk >> 4;          // batch
  const int c    = blk & 15;          // window; XCD = blk%8 = c%8 (L2 pinning)
  const int lane = threadIdx.x;

  const float4* x4 = (const float4*)(x + (size_t)b * CC);
  const float4* y4 = (const float4*)(y + (size_t)b * CC);

  float4 xq[4], yq[4];
#pragma unroll
  for (int cc = 0; cc < 4; ++cc) {
    xq[cc] = x4[lane + 64 * cc];
    yq[cc] = y4[lane + 64 * cc];
  }

  // w = x^2 * y (y in {0,1} -> exact). Lane owns cols 4*(lane+64cc)+q.
  float w[4][4];
#pragma unroll
  for (int cc = 0; cc < 4; ++cc) {
    w[cc][0] = xq[cc].x * xq[cc].x * yq[cc].x;
    w[cc][1] = xq[cc].y * xq[cc].y * yq[cc].y;
    w[cc][2] = xq[cc].z * xq[cc].z * yq[cc].z;
    w[cc][3] = xq[cc].w * xq[cc].w * yq[cc].w;
  }

  // Window ownership: float4 idx [16c,16c+16) -> lanes l0..l0+15, cc0=c>>2.
  const int cc0 = c >> 2;
  const int l0  = 16 * (c & 3);
  float4 wx, wy;
  switch (cc0) {                      // uniform branch; static reg indexing
    case 0: wx = xq[0]; wy = yq[0]; break;
    case 1: wx = xq[1]; wy = yq[1]; break;
    case 2: wx = xq[2]; wy = yq[2]; break;
    default: wx = xq[3]; wy = yq[3]; break;
  }
  const bool win = (lane >= l0) && (lane < l0 + 16);

  // Ballots -> wave-uniform 64-bit positive mask for this window.
  const unsigned long long b0 = __ballot(win && (wy.x != 0.0f));
  const unsigned long long b1 = __ballot(win && (wy.y != 0.0f));
  const unsigned long long b2 = __ballot(win && (wy.z != 0.0f));
  const unsigned long long b3 = __ballot(win && (wy.w != 0.0f));
  unsigned long long M =  spread4(b0 >> l0)        | (spread4(b1 >> l0) << 1) |
                         (spread4(b2 >> l0) << 2)  | (spread4(b3 >> l0) << 3);

  float acc = 0.0f;

  // ---- negatives: window lanes, own registers only ----
  if (win) {
    if (wy.x == 0.0f) { const float t = wx.x * wx.x; acc += t * t * logf(1.0f - wx.x); }
    if (wy.y == 0.0f) { const float t = wx.y * wx.y; acc += t * t * logf(1.0f - wx.y); }
    if (wy.z == 0.0f) { const float t = wx.z * wx.z; acc += t * t * logf(1.0f - wx.z); }
    if (wy.w == 0.0f) { const float t = wx.w * wx.w; acc += t * t * logf(1.0f - wx.w); }
  }

  // ---- positives: up to 4 rows fused per round, coalesced float4 reads ----
  while (M) {
    int t0 = __builtin_ctzll(M); M &= M - 1;
    int live = 1, t1 = t0, t2 = t0, t3 = t0;
    if (M) { t1 = __builtin_ctzll(M); M &= M - 1; live = 2;
      if (M) { t2 = __builtin_ctzll(M); M &= M - 1; live = 3;
        if (M) { t3 = __builtin_ctzll(M); M &= M - 1; live = 4; } } }

    const float4* r0 = (const float4*)(mask + (size_t)(64 * c + t0) * CC);
    const float4* r1 = (const float4*)(mask + (size_t)(64 * c + t1) * CC);
    const float4* r2 = (const float4*)(mask + (size_t)(64 * c + t2) * CC);
    const float4* r3 = (const float4*)(mask + (size_t)(64 * c + t3) * CC);

    float4 v0[4], v1[4], v2[4], v3[4];
#pragma unroll
    for (int cc = 0; cc < 4; ++cc) {       // 16 independent loads in flight
      v0[cc] = r0[lane + 64 * cc];
      v1[cc] = r1[lane + 64 * cc];
      v2[cc] = r2[lane + 64 * cc];
      v3[cc] = r3[lane + 64 * cc];
    }
    float mm0 = 0.0f, mm1 = 0.0f, mm2 = 0.0f, mm3 = 0.0f;
#pragma unroll
    for (int cc = 0; cc < 4; ++cc) {
      mm0 = fmaxf(mm0, fmaxf(fmaxf(v0[cc].x * w[cc][0], v0[cc].y * w[cc][1]),
                             fmaxf(v0[cc].z * w[cc][2], v0[cc].w * w[cc][3])));
      mm1 = fmaxf(mm1, fmaxf(fmaxf(v1[cc].x * w[cc][0], v1[cc].y * w[cc][1]),
                             fmaxf(v1[cc].z * w[cc][2], v1[cc].w * w[cc][3])));
      mm2 = fmaxf(mm2, fmaxf(fmaxf(v2[cc].x * w[cc][0], v2[cc].y * w[cc][1]),
                             fmaxf(v2[cc].z * w[cc][2], v2[cc].w * w[cc][3])));
      mm3 = fmaxf(mm3, fmaxf(fmaxf(v3[cc].x * w[cc][0], v3[cc].y * w[cc][1]),
                             fmaxf(v3[cc].z * w[cc][2], v3[cc].w * w[cc][3])));
    }

    // Pair (mm0,mm1): half-mux butterfly, 6 steps for both rows.
    float u = (lane < 32) ? mm0 : mm1;
    float v = (lane < 32) ? mm1 : mm0;
    v = __shfl_xor(v, 32, 64);
    u = fmaxf(u, v);
#pragma unroll
    for (int o = 16; o > 0; o >>= 1)
      u = fmaxf(u, __shfl_xor(u, o, 64));
    if (lane == 0)               acc += logf(u);    // mm0 (diag => mm>0)
    if (lane == 32 && live >= 2) acc += logf(u);    // mm1

    if (live >= 3) {                                 // uniform branch
      float p = (lane < 32) ? mm2 : mm3;
      float q = (lane < 32) ? mm3 : mm2;
      q = __shfl_xor(q, 32, 64);
      p = fmaxf(p, q);
#pragma unroll
      for (int o = 16; o > 0; o >>= 1)
        p = fmaxf(p, __shfl_xor(p, o, 64));
      if (lane == 1)               acc += logf(p);  // mm2
      if (lane == 33 && live >= 4) acc += logf(p);  // mm3
    }
  }

  // ---- wave reduce, publish ----
#pragma unroll
  for (int o = 32; o > 0; o >>= 1)
    acc += __shfl_down(acc, o, 64);
  if (lane == 0) partial[blk] = acc;
}

// Deterministic NBLK -> 1 reduction, negated mean. float4 loads.
__global__ __launch_bounds__(256) void asl_final_kernel(
    const float* __restrict__ partial, float* __restrict__ out) {
  const int tid = threadIdx.x;
  const float4* p4 = (const float4*)partial;
  float v = 0.0f;
#pragma unroll
  for (int r = 0; r < NBLK / 4 / 256; ++r) {
    const float4 q = p4[tid + 256 * r];
    v += (q.x + q.y) + (q.z + q.w);
  }
#pragma unroll
  for (int o = 32; o > 0; o >>= 1)
    v += __shfl_down(v, o, 64);
  __shared__ float s[4];
  if ((tid & 63) == 0) s[tid >> 6] = v;
  __syncthreads();
  if (tid == 0) out[0] = -(s[0] + s[1] + s[2] + s[3]) * INV_N;
}

extern "C" void kernel_launch(void* const* d_in, const int* in_sizes, int n_in,
                              void* d_out, int out_size, void* d_ws, size_t ws_size,
                              hipStream_t stream) {
  const float* x    = (const float*)d_in[0];
  const float* y    = (const float*)d_in[1];
  const float* mask = (const float*)d_in[2];
  float* out     = (float*)d_out;
  float* partial = (float*)d_ws;   // NBLK floats, fully rewritten each call

  asl_main_kernel<<<NBLK, 64, 0, stream>>>(x, y, mask, partial);
  asl_final_kernel<<<1, 256, 0, stream>>>(partial, out);
}

// Round 13
// 11.444 us; speedup vs baseline: 1.1974x; 1.1974x over previous
//
#include <hip/hip_runtime.h>
#include <math.h>

#define BB 128
#define CC 1024
#define SPLIT 16                 // blocks per batch
#define NBLK (BB * SPLIT)        // 2048
#define INV_N (1.0f / (float)(BB * CC))

// R11 compacted-gather structure, SPLIT=16 with FUSE-4 gathers: each block
// owns entries e ≡ chunk (mod 16); all four (e,e+16,e+32,e+48) mask-row
// gathers issue in ONE k-loop (one exposed latency round, R11-proven), then
// two half-mux butterfly reductions (R12-proven exact).
__global__ __launch_bounds__(64) void asl_main_kernel(
    const float* __restrict__ x, const float* __restrict__ y,
    const float* __restrict__ mask, float* __restrict__ partial) {
  const int blk   = blockIdx.x;
  const int b     = blk & (BB - 1);   // consecutive blocks: different batch
  const int chunk = blk >> 7;         // 0..15
  const int lane  = threadIdx.x;

  __shared__ unsigned short jidx[CC];
  __shared__ float          jw[CC];

  const float* xb = x + (size_t)b * CC;
  const float* yb = y + (size_t)b * CC;

  // Full row into registers for compaction.
  const float4* x4 = (const float4*)xb;
  const float4* y4 = (const float4*)yb;
  float4 xq[4], yq[4];
#pragma unroll
  for (int c = 0; c < 4; ++c) {
    xq[c] = x4[lane + 64 * c];
    yq[c] = y4[lane + 64 * c];
  }

  // Negative-term inputs: one i per lane.
  const int   i  = chunk * 64 + lane;
  const float xi = xb[i];
  const float yi = yb[i];

  // ---- compaction: 16 ballots, deterministic order ----
  int base = 0;
#pragma unroll
  for (int c = 0; c < 4; ++c) {
    const float yv[4] = {yq[c].x, yq[c].y, yq[c].z, yq[c].w};
    const float xv[4] = {xq[c].x, xq[c].y, xq[c].z, xq[c].w};
#pragma unroll
    for (int q = 0; q < 4; ++q) {
      const bool p = (yv[q] != 0.0f);
      const unsigned long long bal = __ballot(p);
      if (p) {
        const int pos = base + __popcll(bal & ((1ull << lane) - 1ull));
        jidx[pos] = (unsigned short)(4 * (lane + 64 * c) + q);
        jw[pos]   = xv[q] * xv[q];
      }
      base += __popcll(bal);
    }
  }
  const int n = base;  // wave-uniform

  float acc = 0.0f;

  // ---- positives: 4-way fused gathers, one latency round per 4 entries ----
  for (int e = chunk; e < n; e += 4 * SPLIT) {
    const int  e1 = e + SPLIT,  e2 = e + 2 * SPLIT,  e3 = e + 3 * SPLIT;
    const bool h1 = (e1 < n),   h2 = (e2 < n),       h3 = (e3 < n);
    const float* r0 = mask + (size_t)jidx[e] * CC;              // uniform
    const float* r1 = h1 ? mask + (size_t)jidx[e1] * CC : r0;   // safe ptrs
    const float* r2 = h2 ? mask + (size_t)jidx[e2] * CC : r0;
    const float* r3 = h3 ? mask + (size_t)jidx[e3] * CC : r0;

    float mm0 = 0.0f, mm1 = 0.0f, mm2 = 0.0f, mm3 = 0.0f;
    for (int k = lane; k < n; k += 64) {        // one iter (n <= 64 typ.)
      const int   j = jidx[k];
      const float w = jw[k];
      mm0 = fmaxf(mm0, r0[j] * w);              // mask 0/1; diag => mm>0
      mm1 = fmaxf(mm1, r1[j] * w);
      mm2 = fmaxf(mm2, r2[j] * w);
      mm3 = fmaxf(mm3, r3[j] * w);
    }

    // Half-mux butterflies: (mm0,mm1) then (mm2,mm3), results on 4 lanes.
    float u = (lane < 32) ? mm0 : mm1;
    float v = (lane < 32) ? mm1 : mm0;
    v = __shfl_xor(v, 32, 64);
    u = fmaxf(u, v);
#pragma unroll
    for (int o = 16; o > 0; o >>= 1)
      u = fmaxf(u, __shfl_xor(u, o, 64));
    if (lane == 0)        acc += logf(u);       // e
    if (lane == 32 && h1) acc += logf(u);       // e+16

    if (h2) {                                   // uniform branch
      float p = (lane < 32) ? mm2 : mm3;
      float q = (lane < 32) ? mm3 : mm2;
      q = __shfl_xor(q, 32, 64);
      p = fmaxf(p, q);
#pragma unroll
      for (int o = 16; o > 0; o >>= 1)
        p = fmaxf(p, __shfl_xor(p, o, 64));
      if (lane == 1)        acc += logf(p);     // e+32
      if (lane == 33 && h3) acc += logf(p);     // e+48
    }
  }

  // ---- negatives ----
  if (yi == 0.0f) {
    const float x2 = xi * xi;
    acc += (x2 * x2) * logf(1.0f - xi);         // xp = x; xp^4*log(1-xp)
  }

  // ---- wave reduce, publish ----
#pragma unroll
  for (int o = 32; o > 0; o >>= 1)
    acc += __shfl_down(acc, o, 64);
  if (lane == 0) partial[blk] = acc;
}

// Deterministic NBLK -> 1 reduction, negated mean. float4 loads.
__global__ __launch_bounds__(256) void asl_final_kernel(
    const float* __restrict__ partial, float* __restrict__ out) {
  const int tid = threadIdx.x;
  const float4* p4 = (const float4*)partial;
  float v = 0.0f;
#pragma unroll
  for (int r = 0; r < NBLK / 4 / 256; ++r) {
    const float4 q = p4[tid + 256 * r];
    v += (q.x + q.y) + (q.z + q.w);
  }
#pragma unroll
  for (int o = 32; o > 0; o >>= 1)
    v += __shfl_down(v, o, 64);
  __shared__ float s[4];
  if ((tid & 63) == 0) s[tid >> 6] = v;
  __syncthreads();
  if (tid == 0) out[0] = -(s[0] + s[1] + s[2] + s[3]) * INV_N;
}

extern "C" void kernel_launch(void* const* d_in, const int* in_sizes, int n_in,
                              void* d_out, int out_size, void* d_ws, size_t ws_size,
                              hipStream_t stream) {
  const float* x    = (const float*)d_in[0];
  const float* y    = (const float*)d_in[1];
  const float* mask = (const float*)d_in[2];
  float* out     = (float*)d_out;
  float* partial = (float*)d_ws;   // NBLK floats, fully rewritten each call

  asl_main_kernel<<<NBLK, 64, 0, stream>>>(x, y, mask, partial);
  asl_final_kernel<<<1, 256, 0, stream>>>(partial, out);
}